// Round 3
// baseline (277.530 us; speedup 1.0000x reference)
//
#include <hip/hip_runtime.h>
#include <stdint.h>

// ---------------------------------------------------------------------------
// SelfAttention: out = softmax((x Wq^T)(x Wk^T)^T / sqrt(E)) (x Wv^T)
// B=4, S=2048, E=1024. bf16 MFMA, fp32 accumulate.
// R10: one-phase-lookahead fragment reads = counted lgkm (T4 for the LDS
// counter, not just vmcnt).  R9 serialized LDS-drain and MFMA inside every
// phase via `barrier; lgkmcnt(0); MFMA`.  Now ds_reads issued in phase p
// feed phase p+1's MFMA from separate registers; NO manual lgkmcnt -- the
// compiler emits counted lgkmcnt(N) before each MFMA cluster, so the LDS
// queue drains WHILE the matrix pipe runs.  Schedule per K-tile (BM=128):
//   p0: read B1        | bar | MMA(a0,b0) | bar
//   p1: read A1        | bar | MMA(a0,b1) | bar
//   p2: gll B(kt+2)    | bar | MMA(a1,b0) | vmcnt(4)+bar   <- only VM wait
//   p3: read next A0,B0 from other buffer; gll A(kt+2)
//                      | bar | MMA(a1,b1) | bar
// Chunk lifetimes re-verified for the shifted reads (B chunks free at
// p1-exit, A chunks at p2-exit, next buffer ready at p2-exit's vmcnt).
// sched_barrier(0) fences each MFMA cluster (rule #18: hipcc hoists
// register-only MFMA past inline-asm barriers).
// All GEMMs BM=128: QKV 768 blk = 3 rounds, scores 512 = 2, PV 256 = 1.
// Dispatches: cast, QKV, scores, softmax, PV.
// ---------------------------------------------------------------------------

typedef __attribute__((ext_vector_type(8))) short bf16x8;   // 8 bf16 = 4 VGPRs
typedef __attribute__((ext_vector_type(4))) float f32x4;

__device__ __forceinline__ float bf2f(uint16_t u) {
    return __uint_as_float(((uint32_t)u) << 16);
}
__device__ __forceinline__ uint16_t f2bf(float f) {
    uint32_t u = __float_as_uint(f);
    uint32_t r = u + 0x7FFFu + ((u >> 16) & 1u);   // RNE
    return (uint16_t)(r >> 16);
}

// async global -> LDS, 16 bytes per lane (wave-uniform base + lane*16)
__device__ __forceinline__ void gll16(const void* g, void* l) {
    __builtin_amdgcn_global_load_lds(
        (const __attribute__((address_space(1))) uint32_t*)g,
        (__attribute__((address_space(3))) uint32_t*)l,
        16, 0, 0);
}

// ---- fused cast: x (NX4 float4s) then stacked Wq|Wk|Wv (NW4 each) ---------
__global__ __launch_bounds__(256) void cast_all(const float* __restrict__ x,
                                                const float* __restrict__ Wq,
                                                const float* __restrict__ Wk,
                                                const float* __restrict__ Wv,
                                                uint16_t* __restrict__ xb,
                                                uint16_t* __restrict__ wqkvb,
                                                int NX4, int NW4) {
    int i = blockIdx.x * 256 + threadIdx.x;
    const float* src;
    uint16_t* dst;
    int off;
    if (i < NX4) {
        src = x; dst = xb; off = i;
    } else {
        int j = i - NX4;
        if (j >= 3 * NW4) return;
        int which = j / NW4;              // 0,1,2
        off = j - which * NW4;
        src = (which == 0) ? Wq : (which == 1) ? Wk : Wv;
        dst = wqkvb + (size_t)which * NW4 * 4;
    }
    float4 v = ((const float4*)src)[off];
    ushort4 o;
    o.x = f2bf(v.x); o.y = f2bf(v.y); o.z = f2bf(v.z); o.w = f2bf(v.w);
    ((ushort4*)dst)[off] = o;
}

// ---- row softmax over 2048 bf16 elements, in place, one block per row -----
__global__ __launch_bounds__(256) void softmax_rows(uint16_t* __restrict__ P) {
    const int n = 2048;
    uint16_t* row = P + (size_t)blockIdx.x * n;
    int tid = threadIdx.x;
    int w = tid >> 6, ln = tid & 63;
    float v[8];
    float m = -3.4e38f;
    #pragma unroll
    for (int i = 0; i < 8; i++) { v[i] = bf2f(row[tid + 256 * i]); m = fmaxf(m, v[i]); }
    #pragma unroll
    for (int o = 32; o >= 1; o >>= 1) m = fmaxf(m, __shfl_down(m, o, 64));
    __shared__ float smax[4], ssum[4];
    if (ln == 0) smax[w] = m;
    __syncthreads();
    m = fmaxf(fmaxf(smax[0], smax[1]), fmaxf(smax[2], smax[3]));
    float s = 0.f;
    #pragma unroll
    for (int i = 0; i < 8; i++) { v[i] = __expf(v[i] - m); s += v[i]; }
    #pragma unroll
    for (int o = 32; o >= 1; o >>= 1) s += __shfl_down(s, o, 64);
    if (ln == 0) ssum[w] = s;
    __syncthreads();
    s = ssum[0] + ssum[1] + ssum[2] + ssum[3];
    float inv = 1.f / s;
    #pragma unroll
    for (int i = 0; i < 8; i++) row[tid + 256 * i] = f2bf(v[i] * inv);
}

// ---- NT GEMM: C[M][N] = alpha * A[M][K] * B[N][K]^T  (bf16 in, OutT out) --
// 128x256 tile, BK=64, 8 waves (2M x 4N), per-wave 64x64 output.

#define DS_A0(P_) do { _Pragma("unroll") for (int f_ = 0; f_ < 2; ++f_) { \
    const uint16_t* q_ = (P_) + axbase + f_ * 1024; \
    a0[f_][0] = *(const bf16x8*)(q_ + cs0); \
    a0[f_][1] = *(const bf16x8*)(q_ + cs1); } } while (0)

#define DS_A1(P_) do { _Pragma("unroll") for (int f_ = 0; f_ < 2; ++f_) { \
    const uint16_t* q_ = (P_) + axbase + (2 + f_) * 1024; \
    a1[f_][0] = *(const bf16x8*)(q_ + cs0); \
    a1[f_][1] = *(const bf16x8*)(q_ + cs1); } } while (0)

#define DS_B0(P_) do { _Pragma("unroll") for (int n_ = 0; n_ < 2; ++n_) { \
    const uint16_t* q_ = (P_) + bxbase + n_ * 1024; \
    b0[n_][0] = *(const bf16x8*)(q_ + cs0); \
    b0[n_][1] = *(const bf16x8*)(q_ + cs1); } } while (0)

#define DS_B1(P_) do { _Pragma("unroll") for (int n_ = 0; n_ < 2; ++n_) { \
    const uint16_t* q_ = (P_) + bxbase + (2 + n_) * 1024; \
    b1[n_][0] = *(const bf16x8*)(q_ + cs0); \
    b1[n_][1] = *(const bf16x8*)(q_ + cs1); } } while (0)

#define MMA_(AF_, BF_, I_, J_) do { \
    _Pragma("unroll") for (int f_ = 0; f_ < 2; ++f_) \
    _Pragma("unroll") for (int n_ = 0; n_ < 2; ++n_) { \
        acc[(I_) + f_][(J_) + n_] = __builtin_amdgcn_mfma_f32_16x16x32_bf16( \
            AF_[f_][0], BF_[n_][0], acc[(I_) + f_][(J_) + n_], 0, 0, 0); \
        acc[(I_) + f_][(J_) + n_] = __builtin_amdgcn_mfma_f32_16x16x32_bf16( \
            AF_[f_][1], BF_[n_][1], acc[(I_) + f_][(J_) + n_], 0, 0, 0); } } while (0)

#define MMA00 MMA_(a0, b0, 0, 0)
#define MMA01 MMA_(a0, b1, 0, 2)
#define MMA10 MMA_(a1, b0, 2, 0)
#define MMA11 MMA_(a1, b1, 2, 2)

#define PRIO1 __builtin_amdgcn_s_setprio(1)
#define PRIO0 __builtin_amdgcn_s_setprio(0)
#define BAR   asm volatile("s_barrier" ::: "memory")
#define SB0   __builtin_amdgcn_sched_barrier(0)
#define VMB(n) asm volatile("s_waitcnt vmcnt(" #n ")\n\ts_barrier" ::: "memory")

// One K-tile = 4 phases.  Reads issued in phase p feed phase p+1's MFMA.
// G: stage tile kt+2's chunks into buf cur.  R3: p3 reads tile kt+1's
// a0/b0 from the other buffer.  WT: wait token at p2-exit.
#define KTILE(G, R3, WT) do { \
    const uint16_t* Asb  = &As[cur][0]; \
    const uint16_t* Bsb  = &Bs[cur][0]; \
    const uint16_t* AsbN = &As[cur ^ 1][0]; \
    const uint16_t* BsbN = &Bs[cur ^ 1][0]; \
    /* p0: read B1 (feeds p1) */ \
    DS_B1(Bsb); \
    BAR; SB0; PRIO1; MMA00; PRIO0; SB0; BAR; \
    /* p1: read A1 (feeds p2) */ \
    DS_A1(Asb); \
    BAR; SB0; PRIO1; MMA01; PRIO0; SB0; BAR; \
    /* p2: stage next-next B (B chunks free since p1-exit) */ \
    if (G) { stB(cur, ko2, 0); stB(cur, ko2, 1); stB(cur, ko2, 2); stB(cur, ko2, 3); } \
    BAR; SB0; PRIO1; MMA10; PRIO0; SB0; WT; \
    /* p3: read next tile's A0/B0 (buffer confirmed by WT's vmcnt); */ \
    /*     stage next-next A (A chunks free since p2-exit) */ \
    if (R3) { DS_A0(AsbN); DS_B0(BsbN); } \
    if (G) { stA(cur, ko2, 0); stA(cur, ko2, 1); } \
    BAR; SB0; PRIO1; MMA11; PRIO0; SB0; BAR; \
} while (0)

template <typename OutT>
__global__ __launch_bounds__(512, 2) void gemm_nt(const uint16_t* __restrict__ A,
                                                  const uint16_t* __restrict__ B,
                                                  OutT* __restrict__ C,
                                                  int gx, int gy,
                                                  long lda, long ldb, long ldc,
                                                  int K, float alpha,
                                                  long sA, long sB, long sC,
                                                  uint16_t* __restrict__ VtP,
                                                  int vcol0) {
    // ---- XCD-contiguous swizzle + 4x4 supertile decode (grids %8==0,
    //      gx%4==0 or handled by stpr, gy%4==0) ----
    const int total = gridDim.x;
    const int nb  = blockIdx.x;
    const int per = total >> 3;
    const int g   = (nb & 7) * per + (nb >> 3);
    const int pb  = gx * gy;
    const int bz  = g / pb;
    const int r   = g - bz * pb;
    const int stpr = gx >> 2;
    const int st  = r >> 4;
    const int w   = r & 15;
    const int sty = st / stpr;
    const int stx = st - sty * stpr;
    const int bx  = (stx << 2) + (w & 3);
    const int by  = (sty << 2) + (w >> 2);

    A += (long)bz * sA;
    B += (long)bz * sB;
    C += (long)bz * sC;

    __shared__ uint16_t As[2][128 * 64];   // 2 x 16 KB
    __shared__ uint16_t Bs[2][256 * 64];   // 2 x 32 KB

    const int tid = threadIdx.x;
    const int m0 = by * 128;
    const int n0 = bx * 256;

    // ---- staging addresses: thread t covers (row = t>>3, 16B chunk = t&7)
    // of each 64-row region. Source column pre-swizzled: chunk ^ (row&7).
    const int srow = tid >> 3;
    const int sx   = ((tid & 7) ^ (srow & 7)) << 3;   // element offset
    const uint16_t* Ag = A + (long)(m0 + srow) * lda + sx;
    const uint16_t* Bg = B + (long)(n0 + srow) * ldb + sx;

    // stage one 64-row chunk (8 KB, 1 gll per thread) of tile at col-offset ko
    auto stA = [&](int buf, long ko, int c) {
        gll16(Ag + (long)c * 64 * lda + ko, &As[buf][c * 4096] + tid * 8);
    };
    auto stB = [&](int buf, long ko, int c) {
        gll16(Bg + (long)c * 64 * ldb + ko, &Bs[buf][c * 4096] + tid * 8);
    };

    // ---- fragment-read addresses (swizzled ds_read) ----
    const int wave = tid >> 6, lane = tid & 63;
    const int quad = lane >> 4, l16 = lane & 15;
    const int wm = wave >> 2, wn = wave & 3;          // 2M x 4N wave grid
    const int cs0 = ((quad       ^ (l16 & 7)) << 3);  // k-step 0 chunk
    const int cs1 = (((quad + 4) ^ (l16 & 7)) << 3);  // k-step 1 chunk
    const int axbase = (wm * 64 + l16) * 64;
    const int bxbase = (wn * 64 + l16) * 64;

    const int nk = K / 64;

    f32x4 acc[4][4] = {};
    bf16x8 a0[2][2], a1[2][2];   // A frags: rows 0-31 / 32-63 of wave block
    bf16x8 b0[2][2], b1[2][2];   // B frags: cols 0-31 / 32-63 of wave block

    // ---- prologue: stage tiles 0,1; land tile 0; read its a0/b0 ----
    stB(0, 0, 0);  stB(0, 0, 1);  stB(0, 0, 2);  stB(0, 0, 3);
    stA(0, 0, 0);  stA(0, 0, 1);
    stB(1, 64, 0); stB(1, 64, 1); stB(1, 64, 2); stB(1, 64, 3);
    stA(1, 64, 0); stA(1, 64, 1);
    asm volatile("s_waitcnt vmcnt(6)" ::: "memory");   // tile0 landed
    BAR;
    { const uint16_t* P = &As[0][0]; DS_A0(P); }
    { const uint16_t* Q = &Bs[0][0]; DS_B0(Q); }

    int cur = 0;
    for (int kt = 0; kt < nk - 2; ++kt) {
        const long ko2 = (long)(kt + 2) * 64;
        KTILE(1, 1, VMB(4));
        cur ^= 1;
    }
    {   // tile nk-2: no staging; drain remaining before reading nk-1's buffer
        const long ko2 = 0; (void)ko2;
        KTILE(0, 1, VMB(0));
        cur ^= 1;
    }
    {   // tile nk-1: final
        const long ko2 = 0; (void)ko2;
        KTILE(0, 0, BAR);
    }

    // ---- epilogue: C/D layout col = lane&15, row = quad*4 + reg ----
    if (VtP && n0 >= vcol0) {
        // V region: write transposed, Vt[b][e][s]; 4 consecutive rows per
        // lane are contiguous in s -> one packed ushort4 store per (f,j).
        #pragma unroll
        for (int f = 0; f < 4; ++f) {
            const int row0 = m0 + wm * 64 + f * 16 + quad * 4;
            const int b_   = row0 >> 11;
            const int s_   = row0 & 2047;
            #pragma unroll
            for (int j = 0; j < 4; ++j) {
                const int e = n0 + wn * 64 + j * 16 + l16 - vcol0;
                ushort4 o;
                o.x = f2bf(acc[f][j][0]);
                o.y = f2bf(acc[f][j][1]);
                o.z = f2bf(acc[f][j][2]);
                o.w = f2bf(acc[f][j][3]);
                *(ushort4*)(VtP + ((long)b_ * 1024 + e) * 2048 + s_) = o;
            }
        }
    } else {
        #pragma unroll
        for (int f = 0; f < 4; ++f) {
            #pragma unroll
            for (int j = 0; j < 4; ++j) {
                #pragma unroll
                for (int r4 = 0; r4 < 4; ++r4) {
                    const int row = m0 + wm * 64 + f * 16 + quad * 4 + r4;
                    const int col = n0 + wn * 64 + j * 16 + l16;
                    const float val = acc[f][j][r4] * alpha;
                    if constexpr (sizeof(OutT) == 2)
                        C[(long)row * ldc + col] = f2bf(val);
                    else
                        C[(long)row * ldc + col] = val;
                }
            }
        }
    }
}

// ---------------------------------------------------------------------------
extern "C" void kernel_launch(void* const* d_in, const int* in_sizes, int n_in,
                              void* d_out, int out_size, void* d_ws, size_t ws_size,
                              hipStream_t stream) {
    const float* x  = (const float*)d_in[0];
    const float* Wq = (const float*)d_in[1];
    const float* Wk = (const float*)d_in[2];
    const float* Wv = (const float*)d_in[3];
    float* out = (float*)d_out;

    const int Bn = 4, S = 2048, E = 1024;
    const long MS = (long)Bn * S;              // 8192 total rows
    const int  N3 = 3 * E;                     // 3072

    // workspace layout (bf16)
    char* ws = (char*)d_ws;
    uint16_t* xb    = (uint16_t*)ws;  ws += (size_t)MS * E * 2;        // 16 MB
    uint16_t* wqkvb = (uint16_t*)ws;  ws += (size_t)N3 * E * 2;        //  6 MB
    uint16_t* QKb   = (uint16_t*)ws;  ws += (size_t)MS * 2048 * 2;     // 32 MB (Q|K, ld=2048)
    uint16_t* Vt    = (uint16_t*)ws;  ws += (size_t)Bn * E * S * 2;    // 16 MB
    uint16_t* Pb    = (uint16_t*)ws;  ws += (size_t)Bn * S * S * 2;    // 32 MB

    // 1) fused cast to bf16 (x + stacked [Wq;Wk;Wv])
    {
        int NX4 = (int)(MS * E / 4);            // 2097152
        int NW4 = E * E / 4;                    // 262144
        int tot = NX4 + 3 * NW4;
        cast_all<<<dim3((tot + 255) / 256), dim3(256), 0, stream>>>(
            x, Wq, Wk, Wv, xb, wqkvb, NX4, NW4);
    }

    // 2) fused QKV: cols [0,2048) -> QKb (ld 2048); cols [2048,3072) -> Vt
    //    transposed (Vt[b][e][s]).  128x256 tiles: 12 x 64 = 768 blocks
    //    = 3 exact rounds on 256 CUs.
    {
        int gx = N3 / 256, gy = (int)(MS / 128);
        gemm_nt<uint16_t><<<dim3(gx * gy), dim3(512), 0, stream>>>(
            xb, wqkvb, QKb, gx, gy, E, E, 2048, E, 1.f, 0, 0, 0,
            Vt, 2048);
    }

    // 3) scores = (Q K^T) / sqrt(E) per batch, bf16 out.
    //    128x256 tiles: 8 x 16 x 4 = 512 blocks = 2 exact rounds.
    {
        int gx = S / 256, gy = S / 128;
        gemm_nt<uint16_t><<<dim3(gx * gy * Bn), dim3(512), 0, stream>>>(
            QKb, QKb + 1024, Pb, gx, gy, 2048, 2048, S, E, 0.03125f,
            (long)S * 2048, (long)S * 2048, (long)S * S,
            nullptr, 0);
    }

    // 4) softmax rows in place (4*2048 rows of 2048)
    softmax_rows<<<dim3(Bn * S), dim3(256), 0, stream>>>(Pb);

    // 5) out = P * Vt^T (M=2048, N=1024, K=2048 per batch), fp32 out.
    //    128x256 tiles: 4 x 16 x 4 = 256 blocks (one round).
    {
        int gx = E / 256, gy = S / 128;
        gemm_nt<float><<<dim3(gx * gy * Bn), dim3(512), 0, stream>>>(
            Pb, Vt, out, gx, gy, S, S, E, S, 1.f,
            (long)S * S, (long)E * S, (long)S * E,
            nullptr, 0);
    }
}

// Round 4
// 260.245 us; speedup vs baseline: 1.0664x; 1.0664x over previous
//
#include <hip/hip_runtime.h>
#include <stdint.h>

// ---------------------------------------------------------------------------
// SelfAttention: out = softmax((x Wq^T)(x Wk^T)^T / sqrt(E)) (x Wv^T)
// B=4, S=2048, E=1024. bf16 MFMA, fp32 accumulate.
// R11 = R9 source (best measured structure) with QKV+scores moved to the
// BM=256 template path (balanced geometry: 2483 cy MFMA vs 2260 cy LDS per
// K-tile per CU -- m201's verified 62%-MfmaUtil shape).  R9 ran everything
// at BM=128 (LDS-BW-bound: 1242 cy MFMA vs 1536 cy LDS).  R10's lookahead
// reads + SB0 fences regressed and are dropped.
//  - counted vmcnt only: VMB(10) @ p1/p3 (BM=256), VMB(6) @ p3 (BM=128);
//    never 0 in the main loop; last two tiles peeled with partial drains.
//  - tile t+2's chunks issued during tile t at chunk-free barriers:
//    p1 -> A{0,2}, p2 -> B{0..3}, p3 -> A{1,3} (BM=256);
//    p2 -> B, p3 -> A (BM=128).
// Tiles: QKV 256x256 (384 blk = 1.5 rounds), scores 256x256 (256 blk = 1
// round), PV 128x256 (256 blk = 1 round).
// Dispatches: cast, QKV, scores, softmax, PV.
// ---------------------------------------------------------------------------

typedef __attribute__((ext_vector_type(8))) short bf16x8;   // 8 bf16 = 4 VGPRs
typedef __attribute__((ext_vector_type(4))) float f32x4;

__device__ __forceinline__ float bf2f(uint16_t u) {
    return __uint_as_float(((uint32_t)u) << 16);
}
__device__ __forceinline__ uint16_t f2bf(float f) {
    uint32_t u = __float_as_uint(f);
    uint32_t r = u + 0x7FFFu + ((u >> 16) & 1u);   // RNE
    return (uint16_t)(r >> 16);
}

// async global -> LDS, 16 bytes per lane (wave-uniform base + lane*16)
__device__ __forceinline__ void gll16(const void* g, void* l) {
    __builtin_amdgcn_global_load_lds(
        (const __attribute__((address_space(1))) uint32_t*)g,
        (__attribute__((address_space(3))) uint32_t*)l,
        16, 0, 0);
}

// ---- fused cast: x (NX4 float4s) then stacked Wq|Wk|Wv (NW4 each) ---------
__global__ __launch_bounds__(256) void cast_all(const float* __restrict__ x,
                                                const float* __restrict__ Wq,
                                                const float* __restrict__ Wk,
                                                const float* __restrict__ Wv,
                                                uint16_t* __restrict__ xb,
                                                uint16_t* __restrict__ wqkvb,
                                                int NX4, int NW4) {
    int i = blockIdx.x * 256 + threadIdx.x;
    const float* src;
    uint16_t* dst;
    int off;
    if (i < NX4) {
        src = x; dst = xb; off = i;
    } else {
        int j = i - NX4;
        if (j >= 3 * NW4) return;
        int which = j / NW4;              // 0,1,2
        off = j - which * NW4;
        src = (which == 0) ? Wq : (which == 1) ? Wk : Wv;
        dst = wqkvb + (size_t)which * NW4 * 4;
    }
    float4 v = ((const float4*)src)[off];
    ushort4 o;
    o.x = f2bf(v.x); o.y = f2bf(v.y); o.z = f2bf(v.z); o.w = f2bf(v.w);
    ((ushort4*)dst)[off] = o;
}

// ---- row softmax over 2048 bf16 elements, in place, one block per row -----
__global__ __launch_bounds__(256) void softmax_rows(uint16_t* __restrict__ P) {
    const int n = 2048;
    uint16_t* row = P + (size_t)blockIdx.x * n;
    int tid = threadIdx.x;
    int w = tid >> 6, ln = tid & 63;
    float v[8];
    float m = -3.4e38f;
    #pragma unroll
    for (int i = 0; i < 8; i++) { v[i] = bf2f(row[tid + 256 * i]); m = fmaxf(m, v[i]); }
    #pragma unroll
    for (int o = 32; o >= 1; o >>= 1) m = fmaxf(m, __shfl_down(m, o, 64));
    __shared__ float smax[4], ssum[4];
    if (ln == 0) smax[w] = m;
    __syncthreads();
    m = fmaxf(fmaxf(smax[0], smax[1]), fmaxf(smax[2], smax[3]));
    float s = 0.f;
    #pragma unroll
    for (int i = 0; i < 8; i++) { v[i] = __expf(v[i] - m); s += v[i]; }
    #pragma unroll
    for (int o = 32; o >= 1; o >>= 1) s += __shfl_down(s, o, 64);
    if (ln == 0) ssum[w] = s;
    __syncthreads();
    s = ssum[0] + ssum[1] + ssum[2] + ssum[3];
    float inv = 1.f / s;
    #pragma unroll
    for (int i = 0; i < 8; i++) row[tid + 256 * i] = f2bf(v[i] * inv);
}

// ---- NT GEMM: C[M][N] = alpha * A[M][K] * B[N][K]^T  (bf16 in, OutT out) --

#define DS_A(mh_) do { \
    _Pragma("unroll") for (int f_ = 0; f_ < MH; ++f_) { \
        const uint16_t* p_ = Asb + axbase + ((mh_)*MH + f_) * 1024; \
        af[f_][0] = *(const bf16x8*)(p_ + cs0); \
        af[f_][1] = *(const bf16x8*)(p_ + cs1); \
    } } while (0)

#define DS_B(nh_) do { \
    _Pragma("unroll") for (int n_ = 0; n_ < 2; ++n_) { \
        const uint16_t* p_ = Bsb + bxbase + ((nh_)*2 + n_) * 1024; \
        bfr[nh_][n_][0] = *(const bf16x8*)(p_ + cs0); \
        bfr[nh_][n_][1] = *(const bf16x8*)(p_ + cs1); \
    } } while (0)

#define MMA(mh_, nh_) do { \
    _Pragma("unroll") for (int f_ = 0; f_ < MH; ++f_) { \
        _Pragma("unroll") for (int n_ = 0; n_ < 2; ++n_) { \
            acc[(mh_)*MH + f_][(nh_)*2 + n_] = __builtin_amdgcn_mfma_f32_16x16x32_bf16( \
                af[f_][0], bfr[nh_][n_][0], acc[(mh_)*MH + f_][(nh_)*2 + n_], 0, 0, 0); \
            acc[(mh_)*MH + f_][(nh_)*2 + n_] = __builtin_amdgcn_mfma_f32_16x16x32_bf16( \
                af[f_][1], bfr[nh_][n_][1], acc[(mh_)*MH + f_][(nh_)*2 + n_], 0, 0, 0); \
        } } } while (0)

#define PH_ENTER do { \
    asm volatile("s_barrier\n\ts_waitcnt lgkmcnt(0)" ::: "memory"); \
    __builtin_amdgcn_s_setprio(1); } while (0)

#define PH_EXIT do { \
    __builtin_amdgcn_s_setprio(0); \
    asm volatile("s_barrier" ::: "memory"); } while (0)

#define VMB(n) asm volatile("s_waitcnt vmcnt(" #n ")\n\ts_barrier" ::: "memory")
#define BARO   asm volatile("s_barrier" ::: "memory")
#define NOBAR  ((void)0)

// One K-tile = 4 phases.  ISSUE: stage tile kt+2's chunks (into buf `cur`,
// legal because each chunk's last read was globally confirmed at the barrier
// preceding its issue point).  W1B/W3B: wait+barrier tokens at p1/p3 exits.
#define KTILE(ISSUE, W1B, W3B) do { \
    const uint16_t* Asb = &As[cur][0]; \
    const uint16_t* Bsb = &Bs[cur][0]; \
    /* p0 */ \
    DS_A(0); DS_B(0); \
    PH_ENTER; MMA(0, 0); PH_EXIT; \
    /* p1: issue next-next A phase0-chunks (free since p0-exit) */ \
    DS_B(1); \
    if constexpr (BM == 256) { if (ISSUE) { stA(cur, ko2, 0); stA(cur, ko2, 2); } } \
    PH_ENTER; MMA(0, 1); __builtin_amdgcn_s_setprio(0); W1B; \
    /* p2: issue next-next B chunks (free since p1-exit) */ \
    DS_A(1); \
    if (ISSUE) { stB(cur, ko2, 0); stB(cur, ko2, 1); stB(cur, ko2, 2); stB(cur, ko2, 3); } \
    PH_ENTER; MMA(1, 0); PH_EXIT; \
    /* p3: issue next-next A phase2-chunks (free since p2-exit) */ \
    if (ISSUE) { \
        if constexpr (BM == 256) { stA(cur, ko2, 1); stA(cur, ko2, 3); } \
        else                     { stA(cur, ko2, 0); stA(cur, ko2, 1); } \
    } \
    PH_ENTER; MMA(1, 1); __builtin_amdgcn_s_setprio(0); W3B; \
} while (0)

template <int BM, typename OutT>
__global__ __launch_bounds__(512, 2) void gemm_nt(const uint16_t* __restrict__ A,
                                                  const uint16_t* __restrict__ B,
                                                  OutT* __restrict__ C,
                                                  int gx, int gy,
                                                  long lda, long ldb, long ldc,
                                                  int K, float alpha,
                                                  long sA, long sB, long sC,
                                                  uint16_t* __restrict__ VtP,
                                                  int vcol0) {
    constexpr int MF = BM / 32;   // M fragments per wave
    constexpr int MH = MF / 2;    // per M-half

    // ---- XCD-contiguous swizzle + 4x4 supertile decode (grids %8==0,
    //      gx%4==0, gy%4==0) ----
    const int total = gridDim.x;
    const int nb  = blockIdx.x;
    const int per = total >> 3;
    const int g   = (nb & 7) * per + (nb >> 3);
    const int pb  = gx * gy;
    const int bz  = g / pb;
    const int r   = g - bz * pb;
    const int stpr = gx >> 2;
    const int st  = r >> 4;
    const int w   = r & 15;
    const int sty = st / stpr;
    const int stx = st - sty * stpr;
    const int bx  = (stx << 2) + (w & 3);
    const int by  = (sty << 2) + (w >> 2);

    A += (long)bz * sA;
    B += (long)bz * sB;
    C += (long)bz * sC;

    __shared__ uint16_t As[2][BM * 64];    // 256: 2x32 KB | 128: 2x16 KB
    __shared__ uint16_t Bs[2][256 * 64];   // 2x32 KB

    const int tid = threadIdx.x;
    const int m0 = by * BM;
    const int n0 = bx * 256;

    // ---- staging addresses: thread t covers (row = t>>3, 16B chunk = t&7)
    // of each 64-row region. Source column pre-swizzled: chunk ^ (row&7).
    const int srow = tid >> 3;
    const int sx   = ((tid & 7) ^ (srow & 7)) << 3;   // element offset
    const uint16_t* Ag = A + (long)(m0 + srow) * lda + sx;
    const uint16_t* Bg = B + (long)(n0 + srow) * ldb + sx;

    // stage one 64-row chunk (8 KB, 1 gll per thread) of tile at col-offset ko
    auto stA = [&](int buf, long ko, int c) {
        gll16(Ag + (long)c * 64 * lda + ko, &As[buf][c * 4096] + tid * 8);
    };
    auto stB = [&](int buf, long ko, int c) {
        gll16(Bg + (long)c * 64 * ldb + ko, &Bs[buf][c * 4096] + tid * 8);
    };

    // ---- fragment-read addresses (swizzled ds_read) ----
    const int wave = tid >> 6, lane = tid & 63;
    const int quad = lane >> 4, l16 = lane & 15;
    const int wm = wave >> 2, wn = wave & 3;          // 2M x 4N wave grid
    const int cs0 = ((quad       ^ (l16 & 7)) << 3);  // k-step 0 chunk
    const int cs1 = (((quad + 4) ^ (l16 & 7)) << 3);  // k-step 1 chunk
    const int axbase = (wm * (BM / 2) + l16) * 64;
    const int bxbase = (wn * 64 + l16) * 64;

    const int nk = K / 64;

    f32x4 acc[MF][4] = {};
    bf16x8 af[MH][2];       // current M-half, 2 k-steps
    bf16x8 bfr[2][2][2];    // both N-halves held across all 4 phases

    // ---- prologue: issue tiles 0 and 1 in steady-state chunk order,
    // counted wait retires only tile0's phase0-deadline chunks ----
    if constexpr (BM == 256) {
        stA(0, 0, 0);  stA(0, 0, 2);
        stB(0, 0, 0);  stB(0, 0, 1);  stB(0, 0, 2);  stB(0, 0, 3);
        stA(0, 0, 1);  stA(0, 0, 3);
        stA(1, 64, 0); stA(1, 64, 2);
        stB(1, 64, 0); stB(1, 64, 1); stB(1, 64, 2); stB(1, 64, 3);
        stA(1, 64, 1); stA(1, 64, 3);
        VMB(10);       // retire t0.{a0,a2,b0..b3}; t0.{a1,a3}+t1 stay in flight
    } else {
        stB(0, 0, 0);  stB(0, 0, 1);  stB(0, 0, 2);  stB(0, 0, 3);
        stA(0, 0, 0);  stA(0, 0, 1);
        stB(1, 64, 0); stB(1, 64, 1); stB(1, 64, 2); stB(1, 64, 3);
        stA(1, 64, 0); stA(1, 64, 1);
        VMB(6);        // retire t0's 6; t1's 6 stay in flight
    }

    int cur = 0;
    for (int kt = 0; kt < nk - 2; ++kt) {
        const long ko2 = (long)(kt + 2) * 64;
        if constexpr (BM == 256) { KTILE(1, VMB(10), VMB(10)); }
        else                     { KTILE(1, BARO,    VMB(6));  }
        cur ^= 1;
    }
    {   // peeled tile nk-2: no issues, partial drain
        const long ko2 = 0; (void)ko2;
        if constexpr (BM == 256) { KTILE(0, VMB(8), VMB(2)); }
        else                     { KTILE(0, BARO,   VMB(0)); }
        cur ^= 1;
    }
    {   // peeled tile nk-1: final tile
        const long ko2 = 0; (void)ko2;
        if constexpr (BM == 256) { KTILE(0, VMB(0), NOBAR); }
        else                     { KTILE(0, BARO,   NOBAR); }
    }

    // ---- epilogue: C/D layout col = lane&15, row = quad*4 + reg ----
    if (VtP && n0 >= vcol0) {
        // V region: write transposed, Vt[b][e][s]; 4 consecutive rows per
        // lane are contiguous in s -> one packed ushort4 store per (f,j).
        #pragma unroll
        for (int f = 0; f < MF; ++f) {
            const int row0 = m0 + wm * (BM / 2) + f * 16 + quad * 4;
            const int b_   = row0 >> 11;
            const int s_   = row0 & 2047;
            #pragma unroll
            for (int j = 0; j < 4; ++j) {
                const int e = n0 + wn * 64 + j * 16 + l16 - vcol0;
                ushort4 o;
                o.x = f2bf(acc[f][j][0]);
                o.y = f2bf(acc[f][j][1]);
                o.z = f2bf(acc[f][j][2]);
                o.w = f2bf(acc[f][j][3]);
                *(ushort4*)(VtP + ((long)b_ * 1024 + e) * 2048 + s_) = o;
            }
        }
    } else {
        #pragma unroll
        for (int f = 0; f < MF; ++f) {
            #pragma unroll
            for (int j = 0; j < 4; ++j) {
                #pragma unroll
                for (int r4 = 0; r4 < 4; ++r4) {
                    const int row = m0 + wm * (BM / 2) + f * 16 + quad * 4 + r4;
                    const int col = n0 + wn * 64 + j * 16 + l16;
                    const float val = acc[f][j][r4] * alpha;
                    if constexpr (sizeof(OutT) == 2)
                        C[(long)row * ldc + col] = f2bf(val);
                    else
                        C[(long)row * ldc + col] = val;
                }
            }
        }
    }
}

// ---------------------------------------------------------------------------
extern "C" void kernel_launch(void* const* d_in, const int* in_sizes, int n_in,
                              void* d_out, int out_size, void* d_ws, size_t ws_size,
                              hipStream_t stream) {
    const float* x  = (const float*)d_in[0];
    const float* Wq = (const float*)d_in[1];
    const float* Wk = (const float*)d_in[2];
    const float* Wv = (const float*)d_in[3];
    float* out = (float*)d_out;

    const int Bn = 4, S = 2048, E = 1024;
    const long MS = (long)Bn * S;              // 8192 total rows
    const int  N3 = 3 * E;                     // 3072

    // workspace layout (bf16)
    char* ws = (char*)d_ws;
    uint16_t* xb    = (uint16_t*)ws;  ws += (size_t)MS * E * 2;        // 16 MB
    uint16_t* wqkvb = (uint16_t*)ws;  ws += (size_t)N3 * E * 2;        //  6 MB
    uint16_t* QKb   = (uint16_t*)ws;  ws += (size_t)MS * 2048 * 2;     // 32 MB (Q|K, ld=2048)
    uint16_t* Vt    = (uint16_t*)ws;  ws += (size_t)Bn * E * S * 2;    // 16 MB
    uint16_t* Pb    = (uint16_t*)ws;  ws += (size_t)Bn * S * S * 2;    // 32 MB

    // 1) fused cast to bf16 (x + stacked [Wq;Wk;Wv])
    {
        int NX4 = (int)(MS * E / 4);            // 2097152
        int NW4 = E * E / 4;                    // 262144
        int tot = NX4 + 3 * NW4;
        cast_all<<<dim3((tot + 255) / 256), dim3(256), 0, stream>>>(
            x, Wq, Wk, Wv, xb, wqkvb, NX4, NW4);
    }

    // 2) fused QKV: cols [0,2048) -> QKb (ld 2048); cols [2048,3072) -> Vt
    //    transposed (Vt[b][e][s]).  256x256 tiles: 12 x 32 = 384 blocks.
    {
        int gx = N3 / 256, gy = (int)(MS / 256);
        gemm_nt<256, uint16_t><<<dim3(gx * gy), dim3(512), 0, stream>>>(
            xb, wqkvb, QKb, gx, gy, E, E, 2048, E, 1.f, 0, 0, 0,
            Vt, 2048);
    }

    // 3) scores = (Q K^T) / sqrt(E) per batch, bf16 out.
    //    256x256 tiles: 8 x 8 x 4 = 256 blocks = 1 exact round.
    {
        int gx = S / 256, gy = S / 256;
        gemm_nt<256, uint16_t><<<dim3(gx * gy * Bn), dim3(512), 0, stream>>>(
            QKb, QKb + 1024, Pb, gx, gy, 2048, 2048, S, E, 0.03125f,
            (long)S * 2048, (long)S * 2048, (long)S * S,
            nullptr, 0);
    }

    // 4) softmax rows in place (4*2048 rows of 2048)
    softmax_rows<<<dim3(Bn * S), dim3(256), 0, stream>>>(Pb);

    // 5) out = P * Vt^T (M=2048, N=1024, K=2048 per batch), fp32 out.
    //    128x256 tiles: 4 x 16 x 4 = 256 blocks (one round).
    {
        int gx = E / 256, gy = S / 128;
        gemm_nt<128, float><<<dim3(gx * gy * Bn), dim3(512), 0, stream>>>(
            Pb, Vt, out, gx, gy, S, S, E, S, 1.f,
            (long)S * S, (long)E * S, (long)S * E,
            nullptr, 0);
    }
}

// Round 5
// 260.072 us; speedup vs baseline: 1.0671x; 1.0007x over previous
//
#include <hip/hip_runtime.h>
#include <stdint.h>

// ---------------------------------------------------------------------------
// SelfAttention: out = softmax((x Wq^T)(x Wk^T)^T / sqrt(E)) (x Wv^T)
// B=4, S=2048, E=1024. bf16 MFMA, fp32 accumulate.
// R12: revert to R7's 3-stage ring engine (best measured: 74 us/gemm,
// 256 thr, 48 KB LDS -> 3 blocks/CU implicit overlap), and fix its one
// known defect: 6.3M LDS bank-conflict cycles/dispatch (8-way conflict on
// 64B-row fragment reads).  Fix = row-pair XOR permutation of the LDS
// chunk layout, applied BOTH sides (rule 21): inverse-permuted GLOBAL
// source (gll dest stays tid-linear) + permuted ds_read offset.
//   p(r,q) = (r>>1)*8 + ((q + 4*(r&1)) ^ ((r>>1)&7))   [16B units]
// Read spread: 2 lanes/bank-quad = free (m136).  Numerics identical.
// Also: softmax loads/stores vectorized to bf16x8 (was scalar 2B/lane).
// Schedules R8-R11 (phase-split, counted vmcnt, BM=256) all measured
// 24-29% MfmaUtil at these short-K shapes -- dropped.
// Dispatches: cast, QKV, scores, softmax, PV.
// ---------------------------------------------------------------------------

typedef __attribute__((ext_vector_type(8))) short bf16x8;   // 8 bf16 = 4 VGPRs
typedef __attribute__((ext_vector_type(4))) float f32x4;

__device__ __forceinline__ float bf2f(uint16_t u) {
    return __uint_as_float(((uint32_t)u) << 16);
}
__device__ __forceinline__ uint16_t f2bf(float f) {
    uint32_t u = __float_as_uint(f);
    uint32_t r = u + 0x7FFFu + ((u >> 16) & 1u);   // RNE
    return (uint16_t)(r >> 16);
}

// async global -> LDS, 16 bytes per lane (wave-uniform base + lane*16)
__device__ __forceinline__ void gll16(const void* g, void* l) {
    __builtin_amdgcn_global_load_lds(
        (const __attribute__((address_space(1))) uint32_t*)g,
        (__attribute__((address_space(3))) uint32_t*)l,
        16, 0, 0);
}

// ---- fused cast: x (NX4 float4s) then stacked Wq|Wk|Wv (NW4 each) ---------
__global__ __launch_bounds__(256) void cast_all(const float* __restrict__ x,
                                                const float* __restrict__ Wq,
                                                const float* __restrict__ Wk,
                                                const float* __restrict__ Wv,
                                                uint16_t* __restrict__ xb,
                                                uint16_t* __restrict__ wqkvb,
                                                int NX4, int NW4) {
    int i = blockIdx.x * 256 + threadIdx.x;
    const float* src;
    uint16_t* dst;
    int off;
    if (i < NX4) {
        src = x; dst = xb; off = i;
    } else {
        int j = i - NX4;
        if (j >= 3 * NW4) return;
        int which = j / NW4;              // 0,1,2
        off = j - which * NW4;
        src = (which == 0) ? Wq : (which == 1) ? Wk : Wv;
        dst = wqkvb + (size_t)which * NW4 * 4;
    }
    float4 v = ((const float4*)src)[off];
    ushort4 o;
    o.x = f2bf(v.x); o.y = f2bf(v.y); o.z = f2bf(v.z); o.w = f2bf(v.w);
    ((ushort4*)dst)[off] = o;
}

// ---- row softmax over 2048 bf16 elements, in place, one block per row -----
// Each thread owns 8 CONTIGUOUS elements: one bf16x8 load + one store
// (16 B/lane; was scalar 2B/lane).  Reductions are permutation-invariant.
__global__ __launch_bounds__(256) void softmax_rows(uint16_t* __restrict__ P) {
    uint16_t* row = P + (size_t)blockIdx.x * 2048;
    const int tid = threadIdx.x;
    const int w = tid >> 6, ln = tid & 63;
    bf16x8 xv = *(const bf16x8*)(&row[tid * 8]);
    float v[8];
    float m = -3.4e38f;
    #pragma unroll
    for (int i = 0; i < 8; i++) { v[i] = bf2f((uint16_t)xv[i]); m = fmaxf(m, v[i]); }
    #pragma unroll
    for (int o = 32; o >= 1; o >>= 1) m = fmaxf(m, __shfl_down(m, o, 64));
    __shared__ float smax[4], ssum[4];
    if (ln == 0) smax[w] = m;
    __syncthreads();
    m = fmaxf(fmaxf(smax[0], smax[1]), fmaxf(smax[2], smax[3]));
    float s = 0.f;
    #pragma unroll
    for (int i = 0; i < 8; i++) { v[i] = __expf(v[i] - m); s += v[i]; }
    #pragma unroll
    for (int o = 32; o >= 1; o >>= 1) s += __shfl_down(s, o, 64);
    if (ln == 0) ssum[w] = s;
    __syncthreads();
    s = ssum[0] + ssum[1] + ssum[2] + ssum[3];
    float inv = 1.f / s;
    bf16x8 ov;
    #pragma unroll
    for (int i = 0; i < 8; i++) ov[i] = (short)f2bf(v[i] * inv);
    *(bf16x8*)(&row[tid * 8]) = ov;
}

// ---- NT GEMM: C[M][N] = alpha * A[M][K] * B[N][K]^T  (bf16 in, OutT out) --
// 128x128 tile, BK=32, 4 waves, 4x4 mfma_f32_16x16x32_bf16 per wave.
// 3-stage LDS ring, global_load_lds w16, vmcnt(4)+barrier (depth-2 prefetch,
// newest stage stays in flight across the barrier). 1D grid, XCD-contiguous
// swizzle + 8x8 supertiles.  LDS chunk layout XOR-permuted over row-pairs
// (see header) -> conflict-free fragment reads.  Optional: columns >= vcol0
// written TRANSPOSED into Vt[b][col-vcol0][row%2048] (V output).
#define BM 128
#define BN 128
#define BK 32

template <typename OutT>
__global__ __launch_bounds__(256) void gemm_nt(const uint16_t* __restrict__ A,
                                               const uint16_t* __restrict__ B,
                                               OutT* __restrict__ C,
                                               int gx, int gy,
                                               long lda, long ldb, long ldc,
                                               int K, float alpha,
                                               long sA, long sB, long sC,
                                               uint16_t* __restrict__ VtP,
                                               int vcol0) {
    // ---- XCD-contiguous swizzle + 8x8 supertile decode ----
    const int total = gridDim.x;
    const int n     = blockIdx.x;
    const int per   = total >> 3;
    const int g     = (n & 7) * per + (n >> 3);    // contiguous range per XCD
    const int pb    = gx * gy;                     // blocks per batch (z)
    const int bz    = g / pb;
    const int r     = g - bz * pb;
    const int stpr  = gx >> 3;                     // supertiles per row-band
    const int st    = r >> 6;
    const int w     = r & 63;
    const int sty   = st / stpr;
    const int stx   = st - sty * stpr;
    const int bx    = (stx << 3) + (w & 7);
    const int by    = (sty << 3) + (w >> 3);

    A += (long)bz * sA;
    B += (long)bz * sB;
    C += (long)bz * sC;

    __shared__ uint16_t As[3][BM * BK];   // 3 x 8 KB
    __shared__ uint16_t Bs[3][BM * BK];   // 3 x 8 KB

    const int tid  = threadIdx.x;
    const int m0   = by * BM;
    const int n0   = bx * BN;
    const int wave = tid >> 6;
    const int lane = tid & 63;
    const int quad = lane >> 4;
    const int l16  = lane & 15;
    const int wr   = (wave >> 1) * 64;   // wave row offset in tile
    const int wc   = (wave & 1) * 64;    // wave col offset in tile

    // ---- staging: LDS dest is tid-linear (chunk p = tid, tid+256); the
    // GLOBAL source is the inverse permutation of p(r,q):
    //   e = (p&7) ^ ((p>>3)&7);  sub = e>>2;  q = e&3;  r = 2*(p>>3)+sub.
    // Second chunk (p+256) maps to the same column, row+64.
    const int e_st = (tid & 7) ^ ((tid >> 3) & 7);
    const int srow = ((tid >> 3) << 1) | (e_st >> 2);   // 0..63
    const int scol = (e_st & 3) << 3;                   // 0,8,16,24
    const uint16_t* Ag = A + (long)(m0 + srow) * lda + scol;
    const uint16_t* Bg = B + (long)(n0 + srow) * ldb + scol;
    const long rsA = 64 * lda;
    const long rsB = 64 * ldb;
    const int so0 = tid * 8;              // chunk p = tid
    const int so1 = tid * 8 + 2048;       // chunk p = tid + 256 (rows +64)

    const int nk = K / BK;

    // prologue: prefetch tiles 0 and 1 into slots 0 and 1 (8 loads in flight)
    gll16(Ag,       &As[0][so0]);
    gll16(Ag + rsA, &As[0][so1]);
    gll16(Bg,       &Bs[0][so0]);
    gll16(Bg + rsB, &Bs[0][so1]);
    Ag += BK; Bg += BK;
    gll16(Ag,       &As[1][so0]);
    gll16(Ag + rsA, &As[1][so1]);
    gll16(Bg,       &Bs[1][so0]);
    gll16(Bg + rsB, &Bs[1][so1]);
    Ag += BK; Bg += BK;

    // ---- fragment-read offset (permuted): for row = wr + i*16 + l16,
    // chunk q = quad:  elem = wr*32 + i*512 + h*64 + ((quad+4*sub)^h)*8,
    // h = l16>>1, sub = l16&1.  Per-(quad,l16) constant + imm per i.
    const int h = l16 >> 1;
    const int laneOff = h * 64 + (((quad + ((l16 & 1) << 2)) ^ h) << 3);

    f32x4 acc[4][4] = {};
    int cur = 0, pf = 2;

    for (int k = 0; k < nk; ++k) {
        // retire only the tile we are about to consume (its 4 loads are the
        // oldest); keep the newest 4 in flight across the barrier.
        if (k < nk - 1) {
            asm volatile("s_waitcnt vmcnt(4)\n\ts_barrier" ::: "memory");
        } else {
            asm volatile("s_waitcnt vmcnt(0)\n\ts_barrier" ::: "memory");
        }

        if (k + 2 < nk) {
            gll16(Ag,       &As[pf][so0]);
            gll16(Ag + rsA, &As[pf][so1]);
            gll16(Bg,       &Bs[pf][so0]);
            gll16(Bg + rsB, &Bs[pf][so1]);
            Ag += BK; Bg += BK;
        }

        const uint16_t* Ac = As[cur];
        const uint16_t* Bc = Bs[cur];
        bf16x8 af[4], bfr[4];
        #pragma unroll
        for (int i = 0; i < 4; i++)
            af[i] = *(const bf16x8*)(&Ac[wr * 32 + i * 512 + laneOff]);
        #pragma unroll
        for (int j = 0; j < 4; j++)
            bfr[j] = *(const bf16x8*)(&Bc[wc * 32 + j * 512 + laneOff]);
        #pragma unroll
        for (int i = 0; i < 4; i++)
            #pragma unroll
            for (int j = 0; j < 4; j++)
                acc[i][j] = __builtin_amdgcn_mfma_f32_16x16x32_bf16(af[i], bfr[j], acc[i][j], 0, 0, 0);

        cur = (cur == 2) ? 0 : cur + 1;
        pf  = (pf  == 2) ? 0 : pf + 1;
    }

    // ---- epilogue: C/D layout col = lane&15, row = quad*4 + reg ----
    if (VtP && n0 >= vcol0) {
        // V region: write transposed, Vt[b][e][s], e = col - vcol0,
        // b = row>>11, s = row&2047. 4 consecutive rows (r4) per lane are
        // contiguous in s -> one packed ushort4 (8 B) store per (i,j).
        #pragma unroll
        for (int i = 0; i < 4; i++) {
            const int row0 = m0 + wr + i * 16 + quad * 4;
            const int b    = row0 >> 11;
            const int s    = row0 & 2047;
            #pragma unroll
            for (int j = 0; j < 4; j++) {
                const int e = n0 + wc + j * 16 + l16 - vcol0;
                ushort4 o;
                o.x = f2bf(acc[i][j][0]);
                o.y = f2bf(acc[i][j][1]);
                o.z = f2bf(acc[i][j][2]);
                o.w = f2bf(acc[i][j][3]);
                *(ushort4*)(VtP + ((long)b * 1024 + e) * 2048 + s) = o;
            }
        }
    } else {
        #pragma unroll
        for (int i = 0; i < 4; i++) {
            #pragma unroll
            for (int j = 0; j < 4; j++) {
                #pragma unroll
                for (int r4 = 0; r4 < 4; r4++) {
                    int row = m0 + wr + i * 16 + quad * 4 + r4;
                    int col = n0 + wc + j * 16 + l16;
                    float val = acc[i][j][r4] * alpha;
                    if constexpr (sizeof(OutT) == 2)
                        C[(long)row * ldc + col] = f2bf(val);
                    else
                        C[(long)row * ldc + col] = val;
                }
            }
        }
    }
}

// ---------------------------------------------------------------------------
extern "C" void kernel_launch(void* const* d_in, const int* in_sizes, int n_in,
                              void* d_out, int out_size, void* d_ws, size_t ws_size,
                              hipStream_t stream) {
    const float* x  = (const float*)d_in[0];
    const float* Wq = (const float*)d_in[1];
    const float* Wk = (const float*)d_in[2];
    const float* Wv = (const float*)d_in[3];
    float* out = (float*)d_out;

    const int Bn = 4, S = 2048, E = 1024;
    const long MS = (long)Bn * S;              // 8192 total rows
    const int  N3 = 3 * E;                     // 3072

    // workspace layout (bf16)
    char* ws = (char*)d_ws;
    uint16_t* xb    = (uint16_t*)ws;  ws += (size_t)MS * E * 2;        // 16 MB
    uint16_t* wqkvb = (uint16_t*)ws;  ws += (size_t)N3 * E * 2;        //  6 MB
    uint16_t* QKb   = (uint16_t*)ws;  ws += (size_t)MS * 2048 * 2;     // 32 MB (Q|K, ld=2048)
    uint16_t* Vt    = (uint16_t*)ws;  ws += (size_t)Bn * E * S * 2;    // 16 MB
    uint16_t* Pb    = (uint16_t*)ws;  ws += (size_t)Bn * S * S * 2;    // 32 MB

    dim3 blk(256);

    // 1) fused cast to bf16 (x + stacked [Wq;Wk;Wv])
    {
        int NX4 = (int)(MS * E / 4);            // 2097152
        int NW4 = E * E / 4;                    // 262144
        int tot = NX4 + 3 * NW4;
        cast_all<<<dim3((tot + 255) / 256), blk, 0, stream>>>(
            x, Wq, Wk, Wv, xb, wqkvb, NX4, NW4);
    }

    // 2) fused QKV: cols [0,2048) -> QKb (ld 2048); cols [2048,3072) -> Vt
    //    transposed (Vt[b][e][s])
    {
        int gx = N3 / BN, gy = (int)(MS / BM);   // 24 x 64
        gemm_nt<uint16_t><<<dim3(gx * gy), blk, 0, stream>>>(
            xb, wqkvb, QKb, gx, gy, E, E, 2048, E, 1.f, 0, 0, 0,
            Vt, 2048);
    }

    // 3) scores = (Q K^T) / sqrt(E) per batch, bf16 out
    {
        int gx = S / BN, gy = S / BM;            // 16 x 16, z=4
        gemm_nt<uint16_t><<<dim3(gx * gy * Bn), blk, 0, stream>>>(
            QKb, QKb + 1024, Pb, gx, gy, 2048, 2048, S, E, 0.03125f,
            (long)S * 2048, (long)S * 2048, (long)S * S,
            nullptr, 0);
    }

    // 4) softmax rows in place (4*2048 rows of 2048)
    softmax_rows<<<dim3(Bn * S), blk, 0, stream>>>(Pb);

    // 5) out = P * Vt^T  (M=2048, N=1024, K=2048 per batch), fp32 out
    {
        int gx = E / BN, gy = S / BM;            // 8 x 16, z=4
        gemm_nt<float><<<dim3(gx * gy * Bn), blk, 0, stream>>>(
            Pb, Vt, out, gx, gy, S, S, E, S, 1.f,
            (long)S * S, (long)E * S, (long)S * E,
            nullptr, 0);
    }
}